// Round 11
// baseline (512.226 us; speedup 1.0000x reference)
//
#include <hip/hip_runtime.h>
#include <hip/hip_bf16.h>

#define MD 8192
#define KD 4096
#define ND 4096

typedef __bf16 bf16x8 __attribute__((ext_vector_type(8)));
typedef float f32x4 __attribute__((ext_vector_type(4)));

__device__ __forceinline__ float gelu_ss(float v) {
    float t = 0.7978845608f * fmaf(0.044715f * v * v, v, v);
    float r = t * __builtin_amdgcn_rcpf(1.0f + fabsf(t));
    return 0.5f * v * (1.0f + r);
}

// ---------------------------------------------------------------------------
// fp32 -> bf16 convert (memory-bound; inputs are L3-resident after 1st replay)
// ---------------------------------------------------------------------------
__global__ void cvt_bf16(const float* __restrict__ in, __bf16* __restrict__ out, int n8) {
    int i = blockIdx.x * 256 + threadIdx.x;
    int stride = gridDim.x * 256;
    for (; i < n8; i += stride) {
        const float4* p = (const float4*)(in + (size_t)i * 8);
        float4 a = p[0], b = p[1];
        bf16x8 v;
        v[0]=(__bf16)a.x; v[1]=(__bf16)a.y; v[2]=(__bf16)a.z; v[3]=(__bf16)a.w;
        v[4]=(__bf16)b.x; v[5]=(__bf16)b.y; v[6]=(__bf16)b.z; v[7]=(__bf16)b.w;
        *(bf16x8*)(out + (size_t)i * 8) = v;
    }
}

// ---------------------------------------------------------------------------
// GEMM+epilogue, round 11: 256x256 block, 4 waves (128x128 per wave,
// acc[8][8]=256 VGPR), BK=32, 4 LDS bufs, lead-3 never-drain staging,
// ONE barrier per K-tile, NO manual lgkm / phase barriers / setprio —
// compiler interleaves 16 ds_reads under 64 MFMAs (1242 cyc/SIMD burst).
// ---------------------------------------------------------------------------
#define BMg 256
#define BNg 256
#define BKg 32
#define KTg (KD / BKg)                    // 128
#define NBLKg ((MD / BMg) * (ND / BNg))   // 512

__device__ __forceinline__ void gload_lds16(const void* g, void* l) {
    __builtin_amdgcn_global_load_lds(
        (const __attribute__((address_space(1))) void*)g,
        (__attribute__((address_space(3))) void*)l, 16, 0, 0);
}

__global__ __launch_bounds__(256, 1) void gemm_bf16_lse(
    const __bf16* __restrict__ xb, const __bf16* __restrict__ Wb,
    const float* __restrict__ bias, float* __restrict__ rowsum)
{
    // 4 bufs x [A 256x32 | B 256x32] bf16 = 4 x 32 KiB = 128 KiB
    __shared__ alignas(16) __bf16 lds[4][16384];

    unsigned bid  = blockIdx.x;
    unsigned sbid = (bid & 7u) * (NBLKg / 8u) + (bid >> 3);   // bijective, 512%8==0
    unsigned bm = sbid / (ND / BNg);
    unsigned bn = sbid % (ND / BNg);

    const unsigned tid  = threadIdx.x;
    const unsigned lane = tid & 63u;
    const unsigned wid  = tid >> 6;      // 0..3
    const unsigned wr   = wid >> 1;      // 0..1 -> 128-row half
    const unsigned wc   = wid & 1u;      // 0..1 -> 128-col half
    const unsigned lr   = lane & 15u;
    const unsigned kg   = lane >> 4;
    // fragment 16B slot, swizzle-corrected: (ro>>1)&3 == (lr>>1)&3 for all frags
    const unsigned s16  = (kg ^ ((lr >> 1) & 3u)) * 16u;

    // staging: 2048 chunks/K-tile (A 1024 + B 1024), 8 per thread.
    // chunk row = (tid>>2)+64i, slot = tid&3; global col-slot pre-swizzled
    // cg = (tid&3) ^ ((row>>1)&3) = (tid&3) ^ ((tid>>3)&3)  (i-independent).
    unsigned srow = tid >> 2;
    unsigned cg   = (tid & 3u) ^ ((tid >> 3) & 3u);
    const __bf16* pA = xb + (size_t)(bm * BMg + srow) * KD + cg * 8u;
    const __bf16* pB = Wb + (size_t)(bn * BNg + srow) * KD + cg * 8u;

    f32x4 acc[8][8] = {};

    auto stage = [&](unsigned bsel, int t) {
        #pragma unroll
        for (int i = 0; i < 4; ++i)
            gload_lds16(pA + (size_t)(64 * i) * KD + (size_t)t * 32u,
                        &lds[bsel][(tid + 256u * i) * 8u]);
        #pragma unroll
        for (int i = 0; i < 4; ++i)
            gload_lds16(pB + (size_t)(64 * i) * KD + (size_t)t * 32u,
                        &lds[bsel][8192u + (tid + 256u * i) * 8u]);
    };

    // prologue: tiles 0,1,2 staged (24 loads/thread in flight)
    stage(0, 0);
    stage(1, 1);
    stage(2, 2);

    #pragma unroll 1
    for (int t = 0; t < KTg; ++t) {
        unsigned cb = (unsigned)t & 3u;
        // certify tile t chip-wide; keep t+1,t+2 in flight (never-drain)
        if (t <= KTg - 3)      asm volatile("s_waitcnt vmcnt(16)" ::: "memory");
        else if (t == KTg - 2) asm volatile("s_waitcnt vmcnt(8)" ::: "memory");
        else                   asm volatile("s_waitcnt vmcnt(0)" ::: "memory");
        __builtin_amdgcn_s_barrier();
        __builtin_amdgcn_sched_barrier(0);   // nothing hoists above the barrier

        if (t + 3 < KTg) stage((unsigned)(t + 3) & 3u, t + 3);

        const char* base = (const char*)&lds[cb][0];
        bf16x8 aF[8], bF[8];
        #pragma unroll
        for (int nf = 0; nf < 8; ++nf)
            bF[nf] = *(const bf16x8*)(base + 16384u
                        + (wc * 128u + nf * 16u + lr) * 64u + s16);
        #pragma unroll
        for (int mf = 0; mf < 8; ++mf)
            aF[mf] = *(const bf16x8*)(base
                        + (wr * 128u + mf * 16u + lr) * 64u + s16);
        // 64 MFMA; compiler inserts fine-grained lgkm waits and interleaves
        #pragma unroll
        for (int mf = 0; mf < 8; ++mf)
            #pragma unroll
            for (int nf = 0; nf < 8; ++nf)
                acc[mf][nf] = __builtin_amdgcn_mfma_f32_16x16x32_bf16(
                    aF[mf], bF[nf], acc[mf][nf], 0, 0, 0);
    }

    // ---- epilogue: bias + leaky^2 + gelu^2 + exp + row partial sums ----
    // C/D layout: col = lane&15 (=lr), row = kg*4 + j
    unsigned row_base = bm * BMg + wr * 128u;
    unsigned col_base = bn * BNg + wc * 128u;
    float bb[8];
    #pragma unroll
    for (int nf = 0; nf < 8; ++nf) bb[nf] = bias[col_base + nf * 16u + lr];
    #pragma unroll
    for (int mf = 0; mf < 8; ++mf) {
        float s[4] = {0.f, 0.f, 0.f, 0.f};
        #pragma unroll
        for (int nf = 0; nf < 8; ++nf) {
            #pragma unroll
            for (int j = 0; j < 4; ++j) {
                float v = acc[mf][nf][j] + bb[nf];
                v = v > 0.0f ? v : 1e-4f * v;        // two leaky-relus fused
                v = gelu_ss(gelu_ss(v));
                s[j] += __expf(v);
            }
        }
        #pragma unroll
        for (int j = 0; j < 4; ++j) {
            float t = s[j];
            t += __shfl_xor(t, 1);
            t += __shfl_xor(t, 2);
            t += __shfl_xor(t, 4);
            t += __shfl_xor(t, 8);
            if (lr == 0)
                atomicAdd(&rowsum[row_base + mf * 16u + kg * 4u + j], t);
        }
    }
}

// ---------------------------------------------------------------------------
// Fallback (round-2 kernel): fused fp32 staging, used only if ws too small.
// ---------------------------------------------------------------------------
#define BM 256
#define BN 256
#define BK 64
#define NBLK ((MD / BM) * (ND / BN))

__device__ __forceinline__ unsigned swz(unsigned row, unsigned kbyte) {
    return row * (BK * 2u) + (kbyte ^ ((row & 7u) << 4));
}

__global__ __launch_bounds__(512, 1) void fused_gemm_lse(
    const float* __restrict__ x, const float* __restrict__ W,
    const float* __restrict__ bias, float* __restrict__ rowsum)
{
    __shared__ alignas(16) __bf16 lds[2][2][BM * BK];
    unsigned bid  = blockIdx.x;
    unsigned sbid = (bid & 7u) * (NBLK / 8u) + (bid >> 3);
    unsigned bm = sbid / (ND / BN);
    unsigned bn = sbid % (ND / BN);
    const unsigned tid  = threadIdx.x;
    const unsigned lane = tid & 63u;
    const unsigned wid  = tid >> 6;
    const unsigned wr   = wid >> 2;
    const unsigned wc   = wid & 3u;
    const unsigned lr   = lane & 15u;
    const unsigned kg   = lane >> 4;
    const float* gA = x + (size_t)bm * BM * KD;
    const float* gB = W + (size_t)bn * BN * KD;
    const unsigned s_row = tid >> 3;
    const unsigned s_c8  = tid & 7u;
    f32x4 acc[8][4] = {};
    float4 ra[8], rb[8];
    auto issue = [&](const float* g, int kt, float4* r) {
        #pragma unroll
        for (int i = 0; i < 4; ++i) {
            unsigned row = s_row + 64u * i;
            size_t goff = (size_t)row * KD + (size_t)kt * BK + (size_t)s_c8 * 8u;
            r[i * 2]     = *(const float4*)(g + goff);
            r[i * 2 + 1] = *(const float4*)(g + goff + 4);
        }
    };
    auto writeT = [&](char* dst, const float4* r) {
        #pragma unroll
        for (int i = 0; i < 4; ++i) {
            unsigned row = s_row + 64u * i;
            float4 lo = r[i * 2], hi = r[i * 2 + 1];
            bf16x8 v;
            v[0]=(__bf16)lo.x; v[1]=(__bf16)lo.y; v[2]=(__bf16)lo.z; v[3]=(__bf16)lo.w;
            v[4]=(__bf16)hi.x; v[5]=(__bf16)hi.y; v[6]=(__bf16)hi.z; v[7]=(__bf16)hi.w;
            *(bf16x8*)(dst + swz(row, s_c8 * 16u)) = v;
        }
    };
    auto compute = [&](int cur) {
        const char* AsB = (const char*)&lds[cur][0][0];
        const char* BsB = (const char*)&lds[cur][1][0];
        #pragma unroll
        for (int ks = 0; ks < 2; ++ks) {
            unsigned kb = (unsigned)ks * 64u + kg * 16u;
            bf16x8 bfr[4];
            #pragma unroll
            for (int ni = 0; ni < 4; ++ni)
                bfr[ni] = *(const bf16x8*)(BsB + swz(wc * 64u + ni * 16u + lr, kb));
            #pragma unroll
            for (int mh = 0; mh < 2; ++mh) {
                bf16x8 af[4];
                #pragma unroll
                for (int a = 0; a < 4; ++a)
                    af[a] = *(const bf16x8*)(AsB + swz(wr * 128u + mh * 64u + a * 16u + lr, kb));
                #pragma unroll
                for (int a = 0; a < 4; ++a)
                    #pragma unroll
                    for (int ni = 0; ni < 4; ++ni)
                        acc[mh * 4 + a][ni] = __builtin_amdgcn_mfma_f32_16x16x32_bf16(
                            af[a], bfr[ni], acc[mh * 4 + a][ni], 0, 0, 0);
            }
        }
    };
    issue(gA, 0, ra); issue(gB, 0, rb);
    writeT((char*)&lds[0][0][0], ra);
    writeT((char*)&lds[0][1][0], rb);
    __syncthreads();
    int cur = 0;
    for (int kt = 0; kt < KD / BK - 1; ++kt) {
        issue(gA, kt + 1, ra);
        issue(gB, kt + 1, rb);
        compute(cur);
        writeT((char*)&lds[cur ^ 1][0][0], ra);
        writeT((char*)&lds[cur ^ 1][1][0], rb);
        __syncthreads();
        cur ^= 1;
    }
    compute(cur);
    unsigned row_base = bm * BM + wr * 128u;
    unsigned col_base = bn * BN + wc * 64u;
    float bb[4];
    #pragma unroll
    for (int ni = 0; ni < 4; ++ni) bb[ni] = bias[col_base + ni * 16u + lr];
    #pragma unroll
    for (int mi = 0; mi < 8; ++mi) {
        float s[4] = {0.f, 0.f, 0.f, 0.f};
        #pragma unroll
        for (int ni = 0; ni < 4; ++ni) {
            #pragma unroll
            for (int j = 0; j < 4; ++j) {
                float v = acc[mi][ni][j] + bb[ni];
                v = v > 0.0f ? v : 1e-4f * v;
                v = gelu_ss(gelu_ss(v));
                s[j] += __expf(v);
            }
        }
        #pragma unroll
        for (int j = 0; j < 4; ++j) {
            float t = s[j];
            t += __shfl_xor(t, 1);
            t += __shfl_xor(t, 2);
            t += __shfl_xor(t, 4);
            t += __shfl_xor(t, 8);
            if (lr == 0)
                atomicAdd(&rowsum[row_base + mi * 16u + kg * 4u + j], t);
        }
    }
}

__global__ void lse_log(float* __restrict__ out) {
    int i = blockIdx.x * 256 + threadIdx.x;
    if (i < MD) out[i] = logf(out[i]);
}

extern "C" void kernel_launch(void* const* d_in, const int* in_sizes, int n_in,
                              void* d_out, int out_size, void* d_ws, size_t ws_size,
                              hipStream_t stream) {
    (void)in_sizes; (void)n_in; (void)out_size;
    const float* x = (const float*)d_in[0];
    const float* W = (const float*)d_in[1];
    const float* b = (const float*)d_in[2];
    float* out = (float*)d_out;

    hipMemsetAsync(out, 0, (size_t)MD * sizeof(float), stream);

    size_t need = ((size_t)MD * KD + (size_t)ND * KD) * sizeof(__bf16);  // 100.7 MB
    if (ws_size >= need) {
        __bf16* xb = (__bf16*)d_ws;
        __bf16* Wb = xb + (size_t)MD * KD;
        cvt_bf16<<<2048, 256, 0, stream>>>(x, xb, MD * KD / 8);
        cvt_bf16<<<2048, 256, 0, stream>>>(W, Wb, ND * KD / 8);
        gemm_bf16_lse<<<NBLKg, 256, 0, stream>>>(xb, Wb, b, out);
    } else {
        fused_gemm_lse<<<NBLK, 512, 0, stream>>>(x, W, b, out);
    }
    lse_log<<<MD / 256, 256, 0, stream>>>(out);
}

// Round 12
// 312.128 us; speedup vs baseline: 1.6411x; 1.6411x over previous
//
#include <hip/hip_runtime.h>
#include <hip/hip_bf16.h>

#define MD 8192
#define KD 4096
#define ND 4096

typedef __bf16 bf16x8 __attribute__((ext_vector_type(8)));
typedef float f32x4 __attribute__((ext_vector_type(4)));

__device__ __forceinline__ float gelu_ss(float v) {
    float t = 0.7978845608f * fmaf(0.044715f * v * v, v, v);
    float r = t * __builtin_amdgcn_rcpf(1.0f + fabsf(t));
    return 0.5f * v * (1.0f + r);
}

// ---------------------------------------------------------------------------
// fp32 -> bf16 convert (memory-bound; inputs are L3-resident after 1st replay)
// ---------------------------------------------------------------------------
__global__ void cvt_bf16(const float* __restrict__ in, __bf16* __restrict__ out, int n8) {
    int i = blockIdx.x * 256 + threadIdx.x;
    int stride = gridDim.x * 256;
    for (; i < n8; i += stride) {
        const float4* p = (const float4*)(in + (size_t)i * 8);
        float4 a = p[0], b = p[1];
        bf16x8 v;
        v[0]=(__bf16)a.x; v[1]=(__bf16)a.y; v[2]=(__bf16)a.z; v[3]=(__bf16)a.w;
        v[4]=(__bf16)b.x; v[5]=(__bf16)b.y; v[6]=(__bf16)b.z; v[7]=(__bf16)b.w;
        *(bf16x8*)(out + (size_t)i * 8) = v;
    }
}

// ---------------------------------------------------------------------------
// GEMM+epilogue, round 12: 256x256, BK=32, 4 LDS bufs, 8 waves (2 per SIMD),
// TILE-LEVEL fragment read-ahead: per tile t -> {vmcnt(4) certify t+1; BAR;
// ds_reads(t+1) into alt reg set; stage(t+3); lgkmcnt(12) [= tile t's reads,
// drained under MFMA(t-1)]; 32 MFMA(t)}. One barrier/tile; no wait in the
// loop ever expects to block in steady state.
// ---------------------------------------------------------------------------
#define BMg 256
#define BNg 256
#define BKg 32
#define KTg (KD / BKg)                    // 128
#define NBLKg ((MD / BMg) * (ND / BNg))   // 512

__device__ __forceinline__ void gload_lds16(const void* g, void* l) {
    __builtin_amdgcn_global_load_lds(
        (const __attribute__((address_space(1))) void*)g,
        (__attribute__((address_space(3))) void*)l, 16, 0, 0);
}

__global__ __launch_bounds__(512, 2) void gemm_bf16_lse(
    const __bf16* __restrict__ xb, const __bf16* __restrict__ Wb,
    const float* __restrict__ bias, float* __restrict__ rowsum)
{
    // [buf=4][A=0/B=1][256*32 bf16] = 128 KiB
    __shared__ alignas(16) __bf16 lds[4][2][BMg * BKg];

    unsigned bid  = blockIdx.x;
    unsigned sbid = (bid & 7u) * (NBLKg / 8u) + (bid >> 3);   // bijective, 512%8==0
    unsigned bm = sbid / (ND / BNg);
    unsigned bn = sbid % (ND / BNg);

    const unsigned tid  = threadIdx.x;
    const unsigned lane = tid & 63u;
    const unsigned wid  = tid >> 6;      // 0..7
    const unsigned wr   = wid >> 2;      // 0..1 -> 128-row half
    const unsigned wc   = wid & 3u;      // 0..3 -> 64-col quarter
    const unsigned lr   = lane & 15u;
    const unsigned kg   = lane >> 4;

    // staging (r9-verified): chunk ch -> row = ch>>2, slot = ch&3; LDS linear
    // (DMA), global col-slot pre-swizzled cg = slot ^ ((row>>1)&3) (rule #21).
    unsigned ch0 = tid, ch1 = tid + 512u;
    unsigned sr0 = ch0 >> 2, cg0 = (ch0 & 3u) ^ ((sr0 >> 1) & 3u);
    unsigned sr1 = ch1 >> 2, cg1 = (ch1 & 3u) ^ ((sr1 >> 1) & 3u);
    const __bf16* gA0 = xb + (size_t)(bm * BMg + sr0) * KD + cg0 * 8u;
    const __bf16* gA1 = xb + (size_t)(bm * BMg + sr1) * KD + cg1 * 8u;
    const __bf16* gB0 = Wb + (size_t)(bn * BNg + sr0) * KD + cg0 * 8u;
    const __bf16* gB1 = Wb + (size_t)(bn * BNg + sr1) * KD + cg1 * 8u;

    f32x4 acc[8][4] = {};

    auto stT = [&](int t) {                      // stage one K-tile (A+B, 4 loads)
        unsigned bsel = (unsigned)t & 3u;
        gload_lds16(gA0 + (size_t)t * 32u, &lds[bsel][0][ch0 * 8u]);
        gload_lds16(gA1 + (size_t)t * 32u, &lds[bsel][0][ch1 * 8u]);
        gload_lds16(gB0 + (size_t)t * 32u, &lds[bsel][1][ch0 * 8u]);
        gload_lds16(gB1 + (size_t)t * 32u, &lds[bsel][1][ch1 * 8u]);
    };
    // fragment reads (r9-verified layout): row stride 64B, slot kg ^ ((ro>>1)&3)
    auto loadA8 = [&](unsigned bsel, bf16x8* dst) {
        const char* As = (const char*)&lds[bsel][0][0];
        #pragma unroll
        for (int mf = 0; mf < 8; ++mf) {
            unsigned ro = wr * 128u + mf * 16u + lr;
            dst[mf] = *(const bf16x8*)(As + ro * 64u + ((kg ^ ((ro >> 1) & 3u)) * 16u));
        }
    };
    auto loadB4 = [&](unsigned bsel, bf16x8* dst) {
        const char* Bs = (const char*)&lds[bsel][1][0];
        #pragma unroll
        for (int nf = 0; nf < 4; ++nf) {
            unsigned ro = wc * 64u + nf * 16u + lr;
            dst[nf] = *(const bf16x8*)(Bs + ro * 64u + ((kg ^ ((ro >> 1) & 3u)) * 16u));
        }
    };
    auto mfma32 = [&](const bf16x8* a8, const bf16x8* b4) {
        __builtin_amdgcn_s_setprio(1);
        #pragma unroll
        for (int mf = 0; mf < 8; ++mf)
            #pragma unroll
            for (int nf = 0; nf < 4; ++nf)
                acc[mf][nf] = __builtin_amdgcn_mfma_f32_16x16x32_bf16(
                    a8[mf], b4[nf], acc[mf][nf], 0, 0, 0);
        __builtin_amdgcn_s_setprio(0);
    };

    bf16x8 aA[8], bA[4], aB[8], bB[4];

    // prologue: stage tiles 0,1,2; certify tile 0 (drain oldest 4 of 12);
    // read tile 0's fragments into set A.
    stT(0); stT(1); stT(2);
    asm volatile("s_waitcnt vmcnt(8)" ::: "memory");
    __builtin_amdgcn_s_barrier();
    loadA8(0, aA); loadB4(0, bA);

    // per-tile body; AC/BC = current frag set (tile t), AN/BN_ = next set.
#define BODY(T, AC, BC, AN, BN_)                                               \
    do {                                                                       \
        int t_ = (T);                                                          \
        /* certify tile t+1 chip-wide; keep t+2(,t+3) in flight */             \
        if (t_ + 2 < KTg)      asm volatile("s_waitcnt vmcnt(4)" ::: "memory");\
        else if (t_ + 1 < KTg) asm volatile("s_waitcnt vmcnt(0)" ::: "memory");\
        __builtin_amdgcn_s_barrier();                                          \
        if (t_ + 1 < KTg) {                                                    \
            unsigned nb_ = (unsigned)(t_ + 1) & 3u;                            \
            loadA8(nb_, AN); loadB4(nb_, BN_);        /* 12 ds_reads */        \
            if (t_ + 3 < KTg) stT(t_ + 3);            /* 4 gloads, post-BAR */ \
            asm volatile("s_waitcnt lgkmcnt(12)" ::: "memory"); /* t's reads */\
        } else {                                                               \
            asm volatile("s_waitcnt lgkmcnt(0)" ::: "memory");                 \
        }                                                                      \
        __builtin_amdgcn_sched_barrier(0);            /* rule #18 fence */     \
        mfma32(AC, BC);                                                        \
    } while (0)

    for (int t = 0; t < KTg; t += 2) {
        BODY(t,     aA, bA, aB, bB);
        BODY(t + 1, aB, bB, aA, bA);
    }
#undef BODY

    // ---- epilogue: bias + leaky^2 + gelu^2 + exp + row partial sums ----
    // C/D layout: col = lane&15 (=lr), row = kg*4 + j
    unsigned row_base = bm * BMg + wr * 128u;
    unsigned col_base = bn * BNg + wc * 64u;
    float bb[4];
    #pragma unroll
    for (int nf = 0; nf < 4; ++nf) bb[nf] = bias[col_base + nf * 16u + lr];
    #pragma unroll
    for (int mf = 0; mf < 8; ++mf) {
        float s[4] = {0.f, 0.f, 0.f, 0.f};
        #pragma unroll
        for (int nf = 0; nf < 4; ++nf) {
            #pragma unroll
            for (int j = 0; j < 4; ++j) {
                float v = acc[mf][nf][j] + bb[nf];
                v = v > 0.0f ? v : 1e-4f * v;      // two leaky-relus fused
                v = gelu_ss(gelu_ss(v));
                s[j] += __expf(v);
            }
        }
        #pragma unroll
        for (int j = 0; j < 4; ++j) {
            float t = s[j];
            t += __shfl_xor(t, 1);
            t += __shfl_xor(t, 2);
            t += __shfl_xor(t, 4);
            t += __shfl_xor(t, 8);
            if (lr == 0)
                atomicAdd(&rowsum[row_base + mf * 16u + kg * 4u + j], t);
        }
    }
}

// ---------------------------------------------------------------------------
// Fallback (round-2 kernel): fused fp32 staging, used only if ws too small.
// ---------------------------------------------------------------------------
#define BM 256
#define BN 256
#define BK 64
#define NBLK ((MD / BM) * (ND / BN))

__device__ __forceinline__ unsigned swz(unsigned row, unsigned kbyte) {
    return row * (BK * 2u) + (kbyte ^ ((row & 7u) << 4));
}

__global__ __launch_bounds__(512, 1) void fused_gemm_lse(
    const float* __restrict__ x, const float* __restrict__ W,
    const float* __restrict__ bias, float* __restrict__ rowsum)
{
    __shared__ alignas(16) __bf16 lds[2][2][BM * BK];
    unsigned bid  = blockIdx.x;
    unsigned sbid = (bid & 7u) * (NBLK / 8u) + (bid >> 3);
    unsigned bm = sbid / (ND / BN);
    unsigned bn = sbid % (ND / BN);
    const unsigned tid  = threadIdx.x;
    const unsigned lane = tid & 63u;
    const unsigned wid  = tid >> 6;
    const unsigned wr   = wid >> 2;
    const unsigned wc   = wid & 3u;
    const unsigned lr   = lane & 15u;
    const unsigned kg   = lane >> 4;
    const float* gA = x + (size_t)bm * BM * KD;
    const float* gB = W + (size_t)bn * BN * KD;
    const unsigned s_row = tid >> 3;
    const unsigned s_c8  = tid & 7u;
    f32x4 acc[8][4] = {};
    float4 ra[8], rb[8];
    auto issue = [&](const float* g, int kt, float4* r) {
        #pragma unroll
        for (int i = 0; i < 4; ++i) {
            unsigned row = s_row + 64u * i;
            size_t goff = (size_t)row * KD + (size_t)kt * BK + (size_t)s_c8 * 8u;
            r[i * 2]     = *(const float4*)(g + goff);
            r[i * 2 + 1] = *(const float4*)(g + goff + 4);
        }
    };
    auto writeT = [&](char* dst, const float4* r) {
        #pragma unroll
        for (int i = 0; i < 4; ++i) {
            unsigned row = s_row + 64u * i;
            float4 lo = r[i * 2], hi = r[i * 2 + 1];
            bf16x8 v;
            v[0]=(__bf16)lo.x; v[1]=(__bf16)lo.y; v[2]=(__bf16)lo.z; v[3]=(__bf16)lo.w;
            v[4]=(__bf16)hi.x; v[5]=(__bf16)hi.y; v[6]=(__bf16)hi.z; v[7]=(__bf16)hi.w;
            *(bf16x8*)(dst + swz(row, s_c8 * 16u)) = v;
        }
    };
    auto compute = [&](int cur) {
        const char* AsB = (const char*)&lds[cur][0][0];
        const char* BsB = (const char*)&lds[cur][1][0];
        #pragma unroll
        for (int ks = 0; ks < 2; ++ks) {
            unsigned kb = (unsigned)ks * 64u + kg * 16u;
            bf16x8 bfr[4];
            #pragma unroll
            for (int ni = 0; ni < 4; ++ni)
                bfr[ni] = *(const bf16x8*)(BsB + swz(wc * 64u + ni * 16u + lr, kb));
            #pragma unroll
            for (int mh = 0; mh < 2; ++mh) {
                bf16x8 af[4];
                #pragma unroll
                for (int a = 0; a < 4; ++a)
                    af[a] = *(const bf16x8*)(AsB + swz(wr * 128u + mh * 64u + a * 16u + lr, kb));
                #pragma unroll
                for (int a = 0; a < 4; ++a)
                    #pragma unroll
                    for (int ni = 0; ni < 4; ++ni)
                        acc[mh * 4 + a][ni] = __builtin_amdgcn_mfma_f32_16x16x32_bf16(
                            af[a], bfr[ni], acc[mh * 4 + a][ni], 0, 0, 0);
            }
        }
    };
    issue(gA, 0, ra); issue(gB, 0, rb);
    writeT((char*)&lds[0][0][0], ra);
    writeT((char*)&lds[0][1][0], rb);
    __syncthreads();
    int cur = 0;
    for (int kt = 0; kt < KD / BK - 1; ++kt) {
        issue(gA, kt + 1, ra);
        issue(gB, kt + 1, rb);
        compute(cur);
        writeT((char*)&lds[cur ^ 1][0][0], ra);
        writeT((char*)&lds[cur ^ 1][1][0], rb);
        __syncthreads();
        cur ^= 1;
    }
    compute(cur);
    unsigned row_base = bm * BM + wr * 128u;
    unsigned col_base = bn * BN + wc * 64u;
    float bb[4];
    #pragma unroll
    for (int ni = 0; ni < 4; ++ni) bb[ni] = bias[col_base + ni * 16u + lr];
    #pragma unroll
    for (int mi = 0; mi < 8; ++mi) {
        float s[4] = {0.f, 0.f, 0.f, 0.f};
        #pragma unroll
        for (int ni = 0; ni < 4; ++ni) {
            #pragma unroll
            for (int j = 0; j < 4; ++j) {
                float v = acc[mi][ni][j] + bb[ni];
                v = v > 0.0f ? v : 1e-4f * v;
                v = gelu_ss(gelu_ss(v));
                s[j] += __expf(v);
            }
        }
        #pragma unroll
        for (int j = 0; j < 4; ++j) {
            float t = s[j];
            t += __shfl_xor(t, 1);
            t += __shfl_xor(t, 2);
            t += __shfl_xor(t, 4);
            t += __shfl_xor(t, 8);
            if (lr == 0)
                atomicAdd(&rowsum[row_base + mi * 16u + kg * 4u + j], t);
        }
    }
}

__global__ void lse_log(float* __restrict__ out) {
    int i = blockIdx.x * 256 + threadIdx.x;
    if (i < MD) out[i] = logf(out[i]);
}

extern "C" void kernel_launch(void* const* d_in, const int* in_sizes, int n_in,
                              void* d_out, int out_size, void* d_ws, size_t ws_size,
                              hipStream_t stream) {
    (void)in_sizes; (void)n_in; (void)out_size;
    const float* x = (const float*)d_in[0];
    const float* W = (const float*)d_in[1];
    const float* b = (const float*)d_in[2];
    float* out = (float*)d_out;

    hipMemsetAsync(out, 0, (size_t)MD * sizeof(float), stream);

    size_t need = ((size_t)MD * KD + (size_t)ND * KD) * sizeof(__bf16);  // 100.7 MB
    if (ws_size >= need) {
        __bf16* xb = (__bf16*)d_ws;
        __bf16* Wb = xb + (size_t)MD * KD;
        cvt_bf16<<<2048, 256, 0, stream>>>(x, xb, MD * KD / 8);
        cvt_bf16<<<2048, 256, 0, stream>>>(W, Wb, ND * KD / 8);
        gemm_bf16_lse<<<NBLKg, 512, 0, stream>>>(xb, Wb, b, out);
    } else {
        fused_gemm_lse<<<NBLK, 512, 0, stream>>>(x, W, b, out);
    }
    lse_log<<<MD / 256, 256, 0, stream>>>(out);
}

// Round 13
// 268.626 us; speedup vs baseline: 1.9068x; 1.1619x over previous
//
#include <hip/hip_runtime.h>
#include <hip/hip_bf16.h>

#define MD 8192
#define KD 4096
#define ND 4096

typedef float f32x4 __attribute__((ext_vector_type(4)));
typedef unsigned long long u64x2 __attribute__((ext_vector_type(2)));
typedef __bf16 bf16x8 __attribute__((ext_vector_type(8)));

__device__ __forceinline__ float gelu_ss(float v) {
    float t = 0.7978845608f * fmaf(0.044715f * v * v, v, v);
    float r = t * __builtin_amdgcn_rcpf(1.0f + fabsf(t));
    return 0.5f * v * (1.0f + r);
}

// ---------------------------------------------------------------------------
// float -> OCP e4m3fn, RNE, saturating. Hand-rolled (no API dependency).
// ---------------------------------------------------------------------------
__device__ __forceinline__ unsigned f32_to_e4m3(float f) {
    unsigned s = (__float_as_uint(f) >> 31) << 7;
    float a = fabsf(f);
    if (a > 448.f) a = 448.f;
    if (a == 0.f) return s;
    unsigned byte;
    int ex; float m = frexpf(a, &ex);          // a = m*2^ex, m in [0.5,1)
    if (ex >= -5) {                            // normal (value >= 2^-6)
        int ri = (int)rintf(m * 16.f);         // [8,16]
        if (ri == 16) { ri = 8; ex += 1; }
        int E = ex - 1 + 7;                    // 1..15
        if (E >= 16) { E = 15; ri = 15; }      // clamp (shouldn't hit)
        byte = (unsigned)((E << 3) | (ri - 8));
    } else {                                   // subnormal, ulp 2^-9
        byte = (unsigned)rintf(a * 512.f);     // 0..8 (8 == 0x08 == 2^-6)
    }
    return s | byte;
}

// fp32 -> fp8 (xscale applied before quantization); 16 elems/thread.
__global__ void cvt_fp8(const float* __restrict__ in, unsigned char* __restrict__ out,
                        float scale, int n16) {
    int i = blockIdx.x * 256 + threadIdx.x;
    int stride = gridDim.x * 256;
    for (; i < n16; i += stride) {
        const float4* p = (const float4*)(in + (size_t)i * 16);
        float4 f0 = p[0], f1 = p[1], f2 = p[2], f3 = p[3];
        float e[16] = {f0.x,f0.y,f0.z,f0.w, f1.x,f1.y,f1.z,f1.w,
                       f2.x,f2.y,f2.z,f2.w, f3.x,f3.y,f3.z,f3.w};
        unsigned long long lo = 0, hi = 0;
        #pragma unroll
        for (int j = 0; j < 8; ++j)
            lo |= (unsigned long long)f32_to_e4m3(e[j] * scale) << (8 * j);
        #pragma unroll
        for (int j = 0; j < 8; ++j)
            hi |= (unsigned long long)f32_to_e4m3(e[8 + j] * scale) << (8 * j);
        u64x2 v; v[0] = lo; v[1] = hi;
        *(u64x2*)(out + (size_t)i * 16) = v;
    }
}

// ---------------------------------------------------------------------------
// GEMM+epilogue, round 13: fp8 e4m3 operands (W pre-scaled x64), 256x256,
// BK=32, 4 LDS bufs (64 KiB -> 2 blocks/CU), r12 tile-level read-ahead flow:
// per tile {vmcnt(2) certify t+1; BAR; 12 ds_read_b64 (t+1); stage(t+3);
// lgkm(12); 32 MFMA fp8}. Halves all LDS bytes vs bf16.
// ---------------------------------------------------------------------------
#define BMg 256
#define BNg 256
#define BKg 32
#define KTg (KD / BKg)                    // 128
#define NBLKg ((MD / BMg) * (ND / BNg))   // 512

__device__ __forceinline__ void gload_lds16(const void* g, void* l) {
    __builtin_amdgcn_global_load_lds(
        (const __attribute__((address_space(1))) void*)g,
        (__attribute__((address_space(3))) void*)l, 16, 0, 0);
}

__global__ __launch_bounds__(512, 2) void gemm_fp8_lse(
    const unsigned char* __restrict__ x8, const unsigned char* __restrict__ W8,
    const float* __restrict__ bias, float* __restrict__ rowsum)
{
    // [buf=4][A=0/B=1][256 rows x 32 cols fp8] = 4 x 2 x 8 KiB = 64 KiB
    __shared__ alignas(16) unsigned char lds[4][2][BMg * BKg];

    unsigned bid  = blockIdx.x;
    unsigned sbid = (bid & 7u) * (NBLKg / 8u) + (bid >> 3);   // bijective
    unsigned bm = sbid / (ND / BNg);
    unsigned bn = sbid % (ND / BNg);

    const unsigned tid  = threadIdx.x;
    const unsigned lane = tid & 63u;
    const unsigned wid  = tid >> 6;      // 0..7
    const unsigned wr   = wid >> 2;      // 0..1 -> 128-row half
    const unsigned wc   = wid & 3u;      // 0..3 -> 64-col quarter
    const unsigned lr   = lane & 15u;
    const unsigned kg   = lane >> 4;

    // staging: 512 chunks(16B)/operand/tile = 1 per thread.
    // chunk -> row = tid>>1, slot = tid&1; LDS linear (DMA); global slot
    // pre-swizzled cg = slot ^ ((row>>2)&1)  (rule #21; involution matches
    // the b64 read swizzle below -> exactly 4 accesses/bank, conflict-free).
    unsigned srow = tid >> 1;
    unsigned cg   = (tid & 1u) ^ ((srow >> 2) & 1u);
    const unsigned char* gA = x8 + (size_t)(bm * BMg + srow) * KD + cg * 16u;
    const unsigned char* gB = W8 + (size_t)(bn * BNg + srow) * KD + cg * 16u;

    f32x4 acc[8][4] = {};

    auto stT = [&](int t) {                      // one K-tile: A+B, 2 gloads
        unsigned bsel = (unsigned)t & 3u;
        gload_lds16(gA + (size_t)t * 32u, &lds[bsel][0][tid * 16u]);
        gload_lds16(gB + (size_t)t * 32u, &lds[bsel][1][tid * 16u]);
    };
    // fragment reads: 8B per frag; addr = ro*32 + swz_slot*16 + (kg&1)*8
    auto loadA8 = [&](unsigned bsel, unsigned long long* dst) {
        const unsigned char* As = &lds[bsel][0][0];
        #pragma unroll
        for (int mf = 0; mf < 8; ++mf) {
            unsigned ro = wr * 128u + mf * 16u + lr;
            dst[mf] = *(const unsigned long long*)(As + ro * 32u
                        + (((kg >> 1) ^ ((ro >> 2) & 1u)) << 4) + ((kg & 1u) << 3));
        }
    };
    auto loadB4 = [&](unsigned bsel, unsigned long long* dst) {
        const unsigned char* Bs = &lds[bsel][1][0];
        #pragma unroll
        for (int nf = 0; nf < 4; ++nf) {
            unsigned ro = wc * 64u + nf * 16u + lr;
            dst[nf] = *(const unsigned long long*)(Bs + ro * 32u
                        + (((kg >> 1) ^ ((ro >> 2) & 1u)) << 4) + ((kg & 1u) << 3));
        }
    };
    auto mfma32 = [&](const unsigned long long* a8, const unsigned long long* b4) {
        __builtin_amdgcn_s_setprio(1);
        #pragma unroll
        for (int mf = 0; mf < 8; ++mf)
            #pragma unroll
            for (int nf = 0; nf < 4; ++nf)
                acc[mf][nf] = __builtin_amdgcn_mfma_f32_16x16x32_fp8_fp8(
                    a8[mf], b4[nf], acc[mf][nf], 0, 0, 0);
        __builtin_amdgcn_s_setprio(0);
    };

    unsigned long long aA[8], bA[4], aB[8], bB[4];

    // prologue: stage tiles 0,1,2 (6 loads); certify tile 0; read its frags.
    stT(0); stT(1); stT(2);
    asm volatile("s_waitcnt vmcnt(4)" ::: "memory");
    __builtin_amdgcn_s_barrier();
    loadA8(0, aA); loadB4(0, bA);

#define BODY(T, AC, BC, AN, BN_)                                               \
    do {                                                                       \
        int t_ = (T);                                                          \
        if (t_ + 2 < KTg)      asm volatile("s_waitcnt vmcnt(2)" ::: "memory");\
        else if (t_ + 1 < KTg) asm volatile("s_waitcnt vmcnt(0)" ::: "memory");\
        __builtin_amdgcn_s_barrier();                                          \
        if (t_ + 1 < KTg) {                                                    \
            unsigned nb_ = (unsigned)(t_ + 1) & 3u;                            \
            loadA8(nb_, AN); loadB4(nb_, BN_);        /* 12 ds_read_b64 */     \
            if (t_ + 3 < KTg) stT(t_ + 3);            /* 2 gloads, post-BAR */ \
            asm volatile("s_waitcnt lgkmcnt(12)" ::: "memory");                \
        } else {                                                               \
            asm volatile("s_waitcnt lgkmcnt(0)" ::: "memory");                 \
        }                                                                      \
        __builtin_amdgcn_sched_barrier(0);            /* rule #18 fence */     \
        mfma32(AC, BC);                                                        \
    } while (0)

    for (int t = 0; t < KTg; t += 2) {
        BODY(t,     aA, bA, aB, bB);
        BODY(t + 1, aB, bB, aA, bA);
    }
#undef BODY

    // ---- epilogue: unscale (W was x64) + bias + leaky^2 + gelu^2 + exp ----
    // C/D layout: col = lane&15 (=lr), row = kg*4 + j
    unsigned row_base = bm * BMg + wr * 128u;
    unsigned col_base = bn * BNg + wc * 64u;
    float bb[4];
    #pragma unroll
    for (int nf = 0; nf < 4; ++nf) bb[nf] = bias[col_base + nf * 16u + lr];
    #pragma unroll
    for (int mf = 0; mf < 8; ++mf) {
        float s[4] = {0.f, 0.f, 0.f, 0.f};
        #pragma unroll
        for (int nf = 0; nf < 4; ++nf) {
            #pragma unroll
            for (int j = 0; j < 4; ++j) {
                float v = fmaf(acc[mf][nf][j], 0.015625f, bb[nf]);  // /64
                v = v > 0.0f ? v : 1e-4f * v;      // two leaky-relus fused
                v = gelu_ss(gelu_ss(v));
                s[j] += __expf(v);
            }
        }
        #pragma unroll
        for (int j = 0; j < 4; ++j) {
            float t = s[j];
            t += __shfl_xor(t, 1);
            t += __shfl_xor(t, 2);
            t += __shfl_xor(t, 4);
            t += __shfl_xor(t, 8);
            if (lr == 0)
                atomicAdd(&rowsum[row_base + mf * 16u + kg * 4u + j], t);
        }
    }
}

// ---------------------------------------------------------------------------
// Fallback (round-2 kernel): fused fp32 staging, used only if ws too small.
// ---------------------------------------------------------------------------
#define BM 256
#define BN 256
#define BK 64
#define NBLK ((MD / BM) * (ND / BN))

__device__ __forceinline__ unsigned swz(unsigned row, unsigned kbyte) {
    return row * (BK * 2u) + (kbyte ^ ((row & 7u) << 4));
}

__global__ __launch_bounds__(512, 1) void fused_gemm_lse(
    const float* __restrict__ x, const float* __restrict__ W,
    const float* __restrict__ bias, float* __restrict__ rowsum)
{
    __shared__ alignas(16) __bf16 lds[2][2][BM * BK];
    unsigned bid  = blockIdx.x;
    unsigned sbid = (bid & 7u) * (NBLK / 8u) + (bid >> 3);
    unsigned bm = sbid / (ND / BN);
    unsigned bn = sbid % (ND / BN);
    const unsigned tid  = threadIdx.x;
    const unsigned lane = tid & 63u;
    const unsigned wid  = tid >> 6;
    const unsigned wr   = wid >> 2;
    const unsigned wc   = wid & 3u;
    const unsigned lr   = lane & 15u;
    const unsigned kg   = lane >> 4;
    const float* gA = x + (size_t)bm * BM * KD;
    const float* gB = W + (size_t)bn * BN * KD;
    const unsigned s_row = tid >> 3;
    const unsigned s_c8  = tid & 7u;
    f32x4 acc[8][4] = {};
    float4 ra[8], rb[8];
    auto issue = [&](const float* g, int kt, float4* r) {
        #pragma unroll
        for (int i = 0; i < 4; ++i) {
            unsigned row = s_row + 64u * i;
            size_t goff = (size_t)row * KD + (size_t)kt * BK + (size_t)s_c8 * 8u;
            r[i * 2]     = *(const float4*)(g + goff);
            r[i * 2 + 1] = *(const float4*)(g + goff + 4);
        }
    };
    auto writeT = [&](char* dst, const float4* r) {
        #pragma unroll
        for (int i = 0; i < 4; ++i) {
            unsigned row = s_row + 64u * i;
            float4 lo = r[i * 2], hi = r[i * 2 + 1];
            bf16x8 v;
            v[0]=(__bf16)lo.x; v[1]=(__bf16)lo.y; v[2]=(__bf16)lo.z; v[3]=(__bf16)lo.w;
            v[4]=(__bf16)hi.x; v[5]=(__bf16)hi.y; v[6]=(__bf16)hi.z; v[7]=(__bf16)hi.w;
            *(bf16x8*)(dst + swz(row, s_c8 * 16u)) = v;
        }
    };
    auto compute = [&](int cur) {
        const char* AsB = (const char*)&lds[cur][0][0];
        const char* BsB = (const char*)&lds[cur][1][0];
        #pragma unroll
        for (int ks = 0; ks < 2; ++ks) {
            unsigned kb = (unsigned)ks * 64u + kg * 16u;
            bf16x8 bfr[4];
            #pragma unroll
            for (int ni = 0; ni < 4; ++ni)
                bfr[ni] = *(const bf16x8*)(BsB + swz(wc * 64u + ni * 16u + lr, kb));
            #pragma unroll
            for (int mh = 0; mh < 2; ++mh) {
                bf16x8 af[4];
                #pragma unroll
                for (int a = 0; a < 4; ++a)
                    af[a] = *(const bf16x8*)(AsB + swz(wr * 128u + mh * 64u + a * 16u + lr, kb));
                #pragma unroll
                for (int a = 0; a < 4; ++a)
                    #pragma unroll
                    for (int ni = 0; ni < 4; ++ni)
                        acc[mh * 4 + a][ni] = __builtin_amdgcn_mfma_f32_16x16x32_bf16(
                            af[a], bfr[ni], acc[mh * 4 + a][ni], 0, 0, 0);
            }
        }
    };
    issue(gA, 0, ra); issue(gB, 0, rb);
    writeT((char*)&lds[0][0][0], ra);
    writeT((char*)&lds[0][1][0], rb);
    __syncthreads();
    int cur = 0;
    for (int kt = 0; kt < KD / BK - 1; ++kt) {
        issue(gA, kt + 1, ra);
        issue(gB, kt + 1, rb);
        compute(cur);
        writeT((char*)&lds[cur ^ 1][0][0], ra);
        writeT((char*)&lds[cur ^ 1][1][0], rb);
        __syncthreads();
        cur ^= 1;
    }
    compute(cur);
    unsigned row_base = bm * BM + wr * 128u;
    unsigned col_base = bn * BN + wc * 64u;
    float bb[4];
    #pragma unroll
    for (int ni = 0; ni < 4; ++ni) bb[ni] = bias[col_base + ni * 16u + lr];
    #pragma unroll
    for (int mi = 0; mi < 8; ++mi) {
        float s[4] = {0.f, 0.f, 0.f, 0.f};
        #pragma unroll
        for (int ni = 0; ni < 4; ++ni) {
            #pragma unroll
            for (int j = 0; j < 4; ++j) {
                float v = acc[mi][ni][j] + bb[ni];
                v = v > 0.0f ? v : 1e-4f * v;
                v = gelu_ss(gelu_ss(v));
                s[j] += __expf(v);
            }
        }
        #pragma unroll
        for (int j = 0; j < 4; ++j) {
            float t = s[j];
            t += __shfl_xor(t, 1);
            t += __shfl_xor(t, 2);
            t += __shfl_xor(t, 4);
            t += __shfl_xor(t, 8);
            if (lr == 0)
                atomicAdd(&rowsum[row_base + mi * 16u + kg * 4u + j], t);
        }
    }
}

__global__ void lse_log(float* __restrict__ out) {
    int i = blockIdx.x * 256 + threadIdx.x;
    if (i < MD) out[i] = logf(out[i]);
}

extern "C" void kernel_launch(void* const* d_in, const int* in_sizes, int n_in,
                              void* d_out, int out_size, void* d_ws, size_t ws_size,
                              hipStream_t stream) {
    (void)in_sizes; (void)n_in; (void)out_size;
    const float* x = (const float*)d_in[0];
    const float* W = (const float*)d_in[1];
    const float* b = (const float*)d_in[2];
    float* out = (float*)d_out;

    hipMemsetAsync(out, 0, (size_t)MD * sizeof(float), stream);

    size_t need = (size_t)MD * KD + (size_t)ND * KD;   // 50.3 MB (fp8)
    if (ws_size >= need) {
        unsigned char* x8 = (unsigned char*)d_ws;
        unsigned char* W8 = x8 + (size_t)MD * KD;
        cvt_fp8<<<2048, 256, 0, stream>>>(x, x8, 1.0f,  MD * KD / 16);
        cvt_fp8<<<2048, 256, 0, stream>>>(W, W8, 64.0f, ND * KD / 16);
        gemm_fp8_lse<<<NBLKg, 512, 0, stream>>>(x8, W8, b, out);
    } else {
        fused_gemm_lse<<<NBLK, 512, 0, stream>>>(x, W, b, out);
    }
    lse_log<<<MD / 256, 256, 0, stream>>>(out);
}

// Round 14
// 250.436 us; speedup vs baseline: 2.0453x; 1.0726x over previous
//
#include <hip/hip_runtime.h>
#include <hip/hip_bf16.h>

#define MD 8192
#define KD 4096
#define ND 4096

typedef float f32x4 __attribute__((ext_vector_type(4)));
typedef unsigned long long u64x2 __attribute__((ext_vector_type(2)));
typedef __bf16 bf16x8 __attribute__((ext_vector_type(8)));

__device__ __forceinline__ float gelu_ss(float v) {
    float t = 0.7978845608f * fmaf(0.044715f * v * v, v, v);
    float r = t * __builtin_amdgcn_rcpf(1.0f + fabsf(t));
    return 0.5f * v * (1.0f + r);
}

// ---------------------------------------------------------------------------
// float -> OCP e4m3fn, RNE, saturating (verified round 13: absmax 0.0).
// ---------------------------------------------------------------------------
__device__ __forceinline__ unsigned f32_to_e4m3(float f) {
    unsigned s = (__float_as_uint(f) >> 31) << 7;
    float a = fabsf(f);
    if (a > 448.f) a = 448.f;
    if (a == 0.f) return s;
    unsigned byte;
    int ex; float m = frexpf(a, &ex);          // a = m*2^ex, m in [0.5,1)
    if (ex >= -5) {                            // normal
        int ri = (int)rintf(m * 16.f);
        if (ri == 16) { ri = 8; ex += 1; }
        int E = ex - 1 + 7;
        if (E >= 16) { E = 15; ri = 15; }
        byte = (unsigned)((E << 3) | (ri - 8));
    } else {
        byte = (unsigned)rintf(a * 512.f);     // subnormal
    }
    return s | byte;
}

// ---------------------------------------------------------------------------
// fp32 -> fp8 with K-INTERLEAVED layout: per 64-k tile, 16B slot s holds
// {k: s*8..s*8+7} ++ {k: 32+s*8..32+s*8+7}. One ds_read_b128 in the GEMM
// then yields a lane's operands for BOTH k-half MFMAs.
// slot index i: row = i>>8 (256 slots/row at K=4096), j=i&255, T=j>>2, s=j&3.
// ---------------------------------------------------------------------------
__global__ void cvt_fp8i(const float* __restrict__ in, unsigned char* __restrict__ out,
                         float scale, int nslots) {
    int i = blockIdx.x * 256 + threadIdx.x;
    int stride = gridDim.x * 256;
    for (; i < nslots; i += stride) {
        int row = i >> 8, j = i & 255;
        int T = j >> 2, s = j & 3;
        const float* src = in + (size_t)row * KD + T * 64 + s * 8;
        float4 a = *(const float4*)src;
        float4 b = *(const float4*)(src + 4);
        float4 c = *(const float4*)(src + 32);
        float4 d = *(const float4*)(src + 36);
        float e0[8] = {a.x,a.y,a.z,a.w, b.x,b.y,b.z,b.w};
        float e1[8] = {c.x,c.y,c.z,c.w, d.x,d.y,d.z,d.w};
        unsigned long long lo = 0, hi = 0;
        #pragma unroll
        for (int q = 0; q < 8; ++q)
            lo |= (unsigned long long)f32_to_e4m3(e0[q] * scale) << (8 * q);
        #pragma unroll
        for (int q = 0; q < 8; ++q)
            hi |= (unsigned long long)f32_to_e4m3(e1[q] * scale) << (8 * q);
        u64x2 v; v[0] = lo; v[1] = hi;
        *(u64x2*)(out + (size_t)i * 16) = v;
    }
}

// ---------------------------------------------------------------------------
// GEMM+epilogue, round 14: fp8, BK=64 (64B rows, byte-identical LDS geometry
// to the 0-conflict bf16 kernel), 2 LDS bufs (64 KiB), tile-level read-ahead:
// body(t) = { vmcnt(0) certify buf(t+1); BAR1; 12 ds_read_b128 (t+1);
// lgkm(12) certify MFMA(t) operands; BAR2 (buf(t) chip-wide dead);
// stage(t+2)->buf(t); 64 MFMA }. Half the sync events of round 13.
// ---------------------------------------------------------------------------
#define BMg 256
#define BNg 256
#define BKg 64
#define KTg (KD / BKg)                    // 64
#define NBLKg ((MD / BMg) * (ND / BNg))   // 512

__device__ __forceinline__ void gload_lds16(const void* g, void* l) {
    __builtin_amdgcn_global_load_lds(
        (const __attribute__((address_space(1))) void*)g,
        (__attribute__((address_space(3))) void*)l, 16, 0, 0);
}

__global__ __launch_bounds__(512, 2) void gemm_fp8_lse(
    const unsigned char* __restrict__ x8, const unsigned char* __restrict__ W8,
    const float* __restrict__ bias, float* __restrict__ rowsum)
{
    // [buf=2][A=0/B=1][256 rows x 64B] = 2 x 2 x 16 KiB = 64 KiB
    __shared__ alignas(16) unsigned char lds[2][2][BMg * BKg];

    unsigned bid  = blockIdx.x;
    unsigned sbid = (bid & 7u) * (NBLKg / 8u) + (bid >> 3);   // bijective
    unsigned bm = sbid / (ND / BNg);
    unsigned bn = sbid % (ND / BNg);

    const unsigned tid  = threadIdx.x;
    const unsigned lane = tid & 63u;
    const unsigned wid  = tid >> 6;      // 0..7
    const unsigned wr   = wid >> 2;      // 0..1 -> 128-row half
    const unsigned wc   = wid & 3u;      // 0..3 -> 64-col quarter
    const unsigned lr   = lane & 15u;
    const unsigned kg   = lane >> 4;

    // staging: 1024 chunks(16B)/operand/tile -> 2 per thread per operand.
    // chunk ch -> LDS row = ch>>2, slot = ch&3 (linear, DMA dest);
    // global slot pre-swizzled sg = slot ^ ((row>>1)&3)  (rule #21; this
    // exact involution measured 0 conflicts in rounds 9/12).
    unsigned ch0 = tid, ch1 = tid + 512u;
    unsigned r0 = ch0 >> 2, sg0 = (ch0 & 3u) ^ ((r0 >> 1) & 3u);
    unsigned r1 = ch1 >> 2, sg1 = (ch1 & 3u) ^ ((r1 >> 1) & 3u);
    const unsigned char* gA0 = x8 + (size_t)(bm * BMg + r0) * KD + sg0 * 16u;
    const unsigned char* gA1 = x8 + (size_t)(bm * BMg + r1) * KD + sg1 * 16u;
    const unsigned char* gB0 = W8 + (size_t)(bn * BNg + r0) * KD + sg0 * 16u;
    const unsigned char* gB1 = W8 + (size_t)(bn * BNg + r1) * KD + sg1 * 16u;

    f32x4 acc[8][4] = {};

    auto stT = [&](int t) {                      // A+B, 4 gloads/thread
        unsigned bsel = (unsigned)t & 1u;
        gload_lds16(gA0 + (size_t)t * 64u, &lds[bsel][0][ch0 * 16u]);
        gload_lds16(gA1 + (size_t)t * 64u, &lds[bsel][0][ch1 * 16u]);
        gload_lds16(gB0 + (size_t)t * 64u, &lds[bsel][1][ch0 * 16u]);
        gload_lds16(gB1 + (size_t)t * 64u, &lds[bsel][1][ch1 * 16u]);
    };
    // fragment reads: one b128 per fragment = both k-half operands (u64x2)
    auto loadA8 = [&](unsigned bsel, u64x2* dst) {
        const unsigned char* As = &lds[bsel][0][0];
        #pragma unroll
        for (int mf = 0; mf < 8; ++mf) {
            unsigned ro = wr * 128u + mf * 16u + lr;
            dst[mf] = *(const u64x2*)(As + ro * 64u + ((kg ^ ((ro >> 1) & 3u)) * 16u));
        }
    };
    auto loadB4 = [&](unsigned bsel, u64x2* dst) {
        const unsigned char* Bs = &lds[bsel][1][0];
        #pragma unroll
        for (int nf = 0; nf < 4; ++nf) {
            unsigned ro = wc * 64u + nf * 16u + lr;
            dst[nf] = *(const u64x2*)(Bs + ro * 64u + ((kg ^ ((ro >> 1) & 3u)) * 16u));
        }
    };
    auto mfma64 = [&](const u64x2* a8, const u64x2* b4) {
        __builtin_amdgcn_s_setprio(1);
        #pragma unroll
        for (int mf = 0; mf < 8; ++mf)
            #pragma unroll
            for (int nf = 0; nf < 4; ++nf) {
                acc[mf][nf] = __builtin_amdgcn_mfma_f32_16x16x32_fp8_fp8(
                    a8[mf][0], b4[nf][0], acc[mf][nf], 0, 0, 0);
                acc[mf][nf] = __builtin_amdgcn_mfma_f32_16x16x32_fp8_fp8(
                    a8[mf][1], b4[nf][1], acc[mf][nf], 0, 0, 0);
            }
        __builtin_amdgcn_s_setprio(0);
    };

    u64x2 aA[8], bA[4], aB[8], bB[4];

    // prologue: stage tiles 0,1; certify 0; read tile 0 fragments.
    stT(0); stT(1);
    asm volatile("s_waitcnt vmcnt(4)" ::: "memory");
    __builtin_amdgcn_s_barrier();
    loadA8(0, aA); loadB4(0, bA);

#define BODY(T, AC, BC, AN, BN_)                                               \
    do {                                                                       \
        int t_ = (T);                                                          \
        /* certify buf(t+1): stage issued a full tile ago -> zero-wait */      \
        asm volatile("s_waitcnt vmcnt(0)" ::: "memory");                       \
        __builtin_amdgcn_s_barrier();          /* BAR1 */                      \
        if (t_ + 1 < KTg) {                                                    \
            loadA8((unsigned)(t_ + 1) & 1u, AN);                               \
            loadB4((unsigned)(t_ + 1) & 1u, BN_);   /* 12 b128, stay in flight*/\
            asm volatile("s_waitcnt lgkmcnt(12)" ::: "memory");                \
        } else {                                                               \
            asm volatile("s_waitcnt lgkmcnt(0)" ::: "memory");                 \
        }                                                                      \
        __builtin_amdgcn_s_barrier();          /* BAR2: buf(t) chip-wide dead*/\
        if (t_ + 2 < KTg) stT(t_ + 2);         /* 4 gloads under MFMA */       \
        __builtin_amdgcn_sched_barrier(0);     /* rule #18 fence */            \
        mfma64(AC, BC);                                                        \
    } while (0)

    for (int t = 0; t < KTg; t += 2) {
        BODY(t,     aA, bA, aB, bB);
        BODY(t + 1, aB, bB, aA, bA);
    }
#undef BODY

    // ---- epilogue: unscale (W was x64) + bias + leaky^2 + gelu^2 + exp ----
    // C/D layout: col = lane&15 (=lr), row = kg*4 + j
    unsigned row_base = bm * BMg + wr * 128u;
    unsigned col_base = bn * BNg + wc * 64u;
    float bb[4];
    #pragma unroll
    for (int nf = 0; nf < 4; ++nf) bb[nf] = bias[col_base + nf * 16u + lr];
    #pragma unroll
    for (int mf = 0; mf < 8; ++mf) {
        float s[4] = {0.f, 0.f, 0.f, 0.f};
        #pragma unroll
        for (int nf = 0; nf < 4; ++nf) {
            #pragma unroll
            for (int j = 0; j < 4; ++j) {
                float v = fmaf(acc[mf][nf][j], 0.015625f, bb[nf]);  // /64
                v = v > 0.0f ? v : 1e-4f * v;      // two leaky-relus fused
                v = gelu_ss(gelu_ss(v));
                s[j] += __expf(v);
            }
        }
        #pragma unroll
        for (int j = 0; j < 4; ++j) {
            float t = s[j];
            t += __shfl_xor(t, 1);
            t += __shfl_xor(t, 2);
            t += __shfl_xor(t, 4);
            t += __shfl_xor(t, 8);
            if (lr == 0)
                atomicAdd(&rowsum[row_base + mf * 16u + kg * 4u + j], t);
        }
    }
}

// ---------------------------------------------------------------------------
// Fallback (round-2 kernel): fused fp32 staging, used only if ws too small.
// ---------------------------------------------------------------------------
#define BM 256
#define BN 256
#define BK 64
#define NBLK ((MD / BM) * (ND / BN))

__device__ __forceinline__ unsigned swz(unsigned row, unsigned kbyte) {
    return row * (BK * 2u) + (kbyte ^ ((row & 7u) << 4));
}

__global__ __launch_bounds__(512, 1) void fused_gemm_lse(
    const float* __restrict__ x, const float* __restrict__ W,
    const float* __restrict__ bias, float* __restrict__ rowsum)
{
    __shared__ alignas(16) __bf16 lds[2][2][BM * BK];
    unsigned bid  = blockIdx.x;
    unsigned sbid = (bid & 7u) * (NBLK / 8u) + (bid >> 3);
    unsigned bm = sbid / (ND / BN);
    unsigned bn = sbid % (ND / BN);
    const unsigned tid  = threadIdx.x;
    const unsigned lane = tid & 63u;
    const unsigned wid  = tid >> 6;
    const unsigned wr   = wid >> 2;
    const unsigned wc   = wid & 3u;
    const unsigned lr   = lane & 15u;
    const unsigned kg   = lane >> 4;
    const float* gA = x + (size_t)bm * BM * KD;
    const float* gB = W + (size_t)bn * BN * KD;
    const unsigned s_row = tid >> 3;
    const unsigned s_c8  = tid & 7u;
    f32x4 acc[8][4] = {};
    float4 ra[8], rb[8];
    auto issue = [&](const float* g, int kt, float4* r) {
        #pragma unroll
        for (int i = 0; i < 4; ++i) {
            unsigned row = s_row + 64u * i;
            size_t goff = (size_t)row * KD + (size_t)kt * BK + (size_t)s_c8 * 8u;
            r[i * 2]     = *(const float4*)(g + goff);
            r[i * 2 + 1] = *(const float4*)(g + goff + 4);
        }
    };
    auto writeT = [&](char* dst, const float4* r) {
        #pragma unroll
        for (int i = 0; i < 4; ++i) {
            unsigned row = s_row + 64u * i;
            float4 lo = r[i * 2], hi = r[i * 2 + 1];
            bf16x8 v;
            v[0]=(__bf16)lo.x; v[1]=(__bf16)lo.y; v[2]=(__bf16)lo.z; v[3]=(__bf16)lo.w;
            v[4]=(__bf16)hi.x; v[5]=(__bf16)hi.y; v[6]=(__bf16)hi.z; v[7]=(__bf16)hi.w;
            *(bf16x8*)(dst + swz(row, s_c8 * 16u)) = v;
        }
    };
    auto compute = [&](int cur) {
        const char* AsB = (const char*)&lds[cur][0][0];
        const char* BsB = (const char*)&lds[cur][1][0];
        #pragma unroll
        for (int ks = 0; ks < 2; ++ks) {
            unsigned kb = (unsigned)ks * 64u + kg * 16u;
            bf16x8 bfr[4];
            #pragma unroll
            for (int ni = 0; ni < 4; ++ni)
                bfr[ni] = *(const bf16x8*)(BsB + swz(wc * 64u + ni * 16u + lr, kb));
            #pragma unroll
            for (int mh = 0; mh < 2; ++mh) {
                bf16x8 af[4];
                #pragma unroll
                for (int a = 0; a < 4; ++a)
                    af[a] = *(const bf16x8*)(AsB + swz(wr * 128u + mh * 64u + a * 16u + lr, kb));
                #pragma unroll
                for (int a = 0; a < 4; ++a)
                    #pragma unroll
                    for (int ni = 0; ni < 4; ++ni)
                        acc[mh * 4 + a][ni] = __builtin_amdgcn_mfma_f32_16x16x32_bf16(
                            af[a], bfr[ni], acc[mh * 4 + a][ni], 0, 0, 0);
            }
        }
    };
    issue(gA, 0, ra); issue(gB, 0, rb);
    writeT((char*)&lds[0][0][0], ra);
    writeT((char*)&lds[0][1][0], rb);
    __syncthreads();
    int cur = 0;
    for (int kt = 0; kt < KD / BK - 1; ++kt) {
        issue(gA, kt + 1, ra);
        issue(gB, kt + 1, rb);
        compute(cur);
        writeT((char*)&lds[cur ^ 1][0][0], ra);
        writeT((char*)&lds[cur ^ 1][1][0], rb);
        __syncthreads();
        cur ^= 1;
    }
    compute(cur);
    unsigned row_base = bm * BM + wr * 128u;
    unsigned col_base = bn * BN + wc * 64u;
    float bb[4];
    #pragma unroll
    for (int ni = 0; ni < 4; ++ni) bb[ni] = bias[col_base + ni * 16u + lr];
    #pragma unroll
    for (int mi = 0; mi < 8; ++mi) {
        float s[4] = {0.f, 0.f, 0.f, 0.f};
        #pragma unroll
        for (int ni = 0; ni < 4; ++ni) {
            #pragma unroll
            for (int j = 0; j < 4; ++j) {
                float v = acc[mi][ni][j] + bb[ni];
                v = v > 0.0f ? v : 1e-4f * v;
                v = gelu_ss(gelu_ss(v));
                s[j] += __expf(v);
            }
        }
        #pragma unroll
        for (int j = 0; j < 4; ++j) {
            float t = s[j];
            t += __shfl_xor(t, 1);
            t += __shfl_xor(t, 2);
            t += __shfl_xor(t, 4);
            t += __shfl_xor(t, 8);
            if (lr == 0)
                atomicAdd(&rowsum[row_base + mi * 16u + kg * 4u + j], t);
        }
    }
}

__global__ void lse_log(float* __restrict__ out) {
    int i = blockIdx.x * 256 + threadIdx.x;
    if (i < MD) out[i] = logf(out[i]);
}

extern "C" void kernel_launch(void* const* d_in, const int* in_sizes, int n_in,
                              void* d_out, int out_size, void* d_ws, size_t ws_size,
                              hipStream_t stream) {
    (void)in_sizes; (void)n_in; (void)out_size;
    const float* x = (const float*)d_in[0];
    const float* W = (const float*)d_in[1];
    const float* b = (const float*)d_in[2];
    float* out = (float*)d_out;

    hipMemsetAsync(out, 0, (size_t)MD * sizeof(float), stream);

    size_t need = (size_t)MD * KD + (size_t)ND * KD;   // 50.3 MB (fp8)
    if (ws_size >= need) {
        unsigned char* x8 = (unsigned char*)d_ws;
        unsigned char* W8 = x8 + (size_t)MD * KD;
        cvt_fp8i<<<2048, 256, 0, stream>>>(x, x8, 1.0f,  MD * KD / 16);
        cvt_fp8i<<<2048, 256, 0, stream>>>(W, W8, 64.0f, ND * KD / 16);
        gemm_fp8_lse<<<NBLKg, 512, 0, stream>>>(x8, W8, b, out);
    } else {
        fused_gemm_lse<<<NBLK, 512, 0, stream>>>(x, W, b, out);
    }
    lse_log<<<MD / 256, 256, 0, stream>>>(out);
}